// Round 2
// baseline (379.935 us; speedup 1.0000x reference)
//
#include <hip/hip_runtime.h>
#include <hip/hip_bf16.h>
#include <hip/hip_fp16.h>

#define BATCH 8
#define NSEQ 1024
#define DIMM 448
#define NHEAD 7
#define HDIM 64
#define MROWS (BATCH*NSEQ)   // 8192
#define KDIM 448
#define SCALE_F 0.125f

typedef short short8 __attribute__((ext_vector_type(8)));
typedef float floatx16 __attribute__((ext_vector_type(16)));

#define MFMA32(a,b,c) __builtin_amdgcn_mfma_f32_32x32x16_bf16(a,b,c,0,0,0)

__device__ __forceinline__ unsigned short f2bf(float f){
    __hip_bfloat16 h = __float2bfloat16(f);
    return *reinterpret_cast<unsigned short*>(&h);
}
__device__ __forceinline__ float bf2f(unsigned short u){
    __hip_bfloat16 h; *reinterpret_cast<unsigned short*>(&h) = u;
    return __bfloat162float(h);
}
__device__ __forceinline__ float h2f(unsigned short u){
    __half h; *reinterpret_cast<unsigned short*>(&h) = u;
    return __half2float(h);
}
__device__ __forceinline__ unsigned short f2h(float f){
    __half h = __float2half(f);
    return *reinterpret_cast<unsigned short*>(&h);
}

// ---------------------------------------------------------------------------
// prep_all: fused conversions (one launch).
//   [0,3584)      : x fp32 -> xh bf16 (1 float4/thread)
//   [3584,4032)   : ek fp32 -> ekh bf16
//   [4032,4228)   : wqv [448][896] -> wqvTh [896][448] bf16  (4x 64-thr units)
//   [4228,4340)   : wout [448][448] -> woTh/woTl [512][448] split bf16
//   [4340,6132)   : eb -> bp fp16, pre-scaled by 0.125, attn granule order
//                   (2x 128-thr units per block)
// bp layout: ((((h*16+qt)*32 + mt)*4 + g2*2 + jj)*512 + lane*8 + t) where
//   score q = qt*64 + g2*32 + (lane&31), m = mt*32 + (t&3)+8*(t>>2)+16*jj+4*(lane>>5)
// ---------------------------------------------------------------------------
__global__ __launch_bounds__(256)
void prep_all(const float* __restrict__ x, const float* __restrict__ ek,
              const float* __restrict__ wqv, const float* __restrict__ wout,
              const float* __restrict__ eb,
              unsigned short* __restrict__ xh, unsigned short* __restrict__ ekh,
              unsigned short* __restrict__ wqvTh, unsigned short* __restrict__ woTh,
              unsigned short* __restrict__ woTl, unsigned short* __restrict__ bp)
{
    __shared__ float T[2][64][33];
    const int bx = blockIdx.x, tid = threadIdx.x;

    if (bx < 3584) {                         // x -> bf16
        int i = bx*256 + tid;
        float4 v = ((const float4*)x)[i];
        ((ushort4*)xh)[i] = make_ushort4(f2bf(v.x), f2bf(v.y), f2bf(v.z), f2bf(v.w));
    } else if (bx < 4032) {                  // ek -> bf16
        int i = (bx-3584)*256 + tid;
        float4 v = ((const float4*)ek)[i];
        ((ushort4*)ekh)[i] = make_ushort4(f2bf(v.x), f2bf(v.y), f2bf(v.z), f2bf(v.w));
    } else if (bx < 4228) {                  // wqv transpose, single bf16
        int lid = (bx-4032)*4 + (tid>>6);    // 0..783 = kc(56) x ng(14)
        int kc = lid % 56, ng = lid / 56;
        int n = ng*64 + (tid&63);
        unsigned short h[8];
#pragma unroll
        for (int j = 0; j < 8; ++j) h[j] = f2bf(wqv[(size_t)(kc*8+j)*896 + n]);
        size_t o = (size_t)n*KDIM + kc*8;
        *(ushort4*)(wqvTh + o)     = make_ushort4(h[0],h[1],h[2],h[3]);
        *(ushort4*)(wqvTh + o + 4) = make_ushort4(h[4],h[5],h[6],h[7]);
    } else if (bx < 4340) {                  // wout transpose, split hi/lo
        int lid = (bx-4228)*4 + (tid>>6);    // 0..447 = kc(56) x ng(8)
        int kc = lid % 56, ng = lid / 56;
        int n = ng*64 + (tid&63);
        ushort4 h0={0,0,0,0}, h1={0,0,0,0}, l0={0,0,0,0}, l1={0,0,0,0};
        if (n < DIMM) {
            unsigned short h[8], l[8];
#pragma unroll
            for (int j = 0; j < 8; ++j) {
                float f = wout[(size_t)(kc*8+j)*DIMM + n];
                h[j] = f2bf(f); l[j] = f2bf(f - bf2f(h[j]));
            }
            h0 = make_ushort4(h[0],h[1],h[2],h[3]); h1 = make_ushort4(h[4],h[5],h[6],h[7]);
            l0 = make_ushort4(l[0],l[1],l[2],l[3]); l1 = make_ushort4(l[4],l[5],l[6],l[7]);
        }
        size_t o = (size_t)n*KDIM + kc*8;
        *(ushort4*)(woTh + o) = h0; *(ushort4*)(woTh + o + 4) = h1;
        *(ushort4*)(woTl + o) = l0; *(ushort4*)(woTl + o + 4) = l1;
    } else {                                 // bias prep
        const int sub = tid >> 7, st = tid & 127;
        const int lid = (bx-4340)*2 + sub;   // 0..3583
        const int mt = lid & 31, qt = (lid>>5) & 15, h = lid >> 9;
#pragma unroll
        for (int it = 0; it < 4; ++it) {
            int idx = it*128 + st;
            int row = idx >> 3, c4 = (idx & 7)*4;
            float4 v = *(const float4*)(eb + ((size_t)(h*NSEQ + qt*64 + row))*NSEQ + mt*32 + c4);
            T[sub][row][c4+0]=v.x; T[sub][row][c4+1]=v.y;
            T[sub][row][c4+2]=v.z; T[sub][row][c4+3]=v.w;
        }
        __syncthreads();
        const int g2 = st >> 6, lane = st & 63;
        const int lq = lane & 31, quad = lane >> 5;
        const int q = g2*32 + lq;
        unsigned short* dst = bp + ((((size_t)h*16 + qt)*32 + mt)*4 + g2*2)*512 + lane*8;
#pragma unroll
        for (int jj = 0; jj < 2; ++jj) {
            unsigned short o[8];
#pragma unroll
            for (int t = 0; t < 8; ++t) {
                int m = (t&3) + 8*(t>>2) + 16*jj + 4*quad;
                o[t] = f2h(T[sub][q][m] * SCALE_F);
            }
            *(ushort4*)(dst + jj*512)     = make_ushort4(o[0],o[1],o[2],o[3]);
            *(ushort4*)(dst + jj*512 + 4) = make_ushort4(o[4],o[5],o[6],o[7]);
        }
    }
}

// ---------------------------------------------------------------------------
// gemm1_reg: qv = x @ w_qv, single bf16, REGISTER-ONLY (no LDS, no barriers).
// 1 wave per block, tile 64x64, BK=32, depth-1 reg prefetch.
// grid (128, 14), block 64. y<7 -> q heads; y>=7 -> vT heads (transposed).
// ---------------------------------------------------------------------------
__global__ __launch_bounds__(64, 2)
void gemm1_reg(const unsigned short* __restrict__ Ah, const unsigned short* __restrict__ Bh,
               unsigned short* __restrict__ qd, unsigned short* __restrict__ vTd)
{
    const int lane = threadIdx.x;
    const int lq = lane & 31, lh = lane >> 5;
    const int m0 = blockIdx.x * 64;
    const int y  = blockIdx.y;
    const int n0 = y * 64;
    const unsigned short* aB = Ah + (size_t)(m0 + lq)*KDIM + lh*8;
    const unsigned short* bB = Bh + (size_t)(n0 + lq)*KDIM + lh*8;

    floatx16 acc[2][2] = {};
    short8 aR[2][2][2], bR[2][2][2];
#define LD1(kt, par) {                                                        \
    _Pragma("unroll") for (int fm = 0; fm < 2; ++fm)                          \
    _Pragma("unroll") for (int c = 0; c < 2; ++c) {                           \
        aR[par][fm][c] = *(const short8*)(aB + (size_t)fm*32*KDIM + (kt)*32 + c*16); \
        bR[par][fm][c] = *(const short8*)(bB + (size_t)fm*32*KDIM + (kt)*32 + c*16); } }

    LD1(0, 0)
#pragma unroll
    for (int kt = 0; kt < 14; ++kt) {
        const int par = kt & 1;
        if (kt < 13) LD1(kt+1, par^1)
#pragma unroll
        for (int c = 0; c < 2; ++c)
#pragma unroll
            for (int fm = 0; fm < 2; ++fm)
#pragma unroll
                for (int fn = 0; fn < 2; ++fn)
                    acc[fm][fn] = MFMA32(aR[par][fm][c], bR[par][fn][c], acc[fm][fn]);
    }
#undef LD1

    if (y < NHEAD) {
#pragma unroll
        for (int fm = 0; fm < 2; ++fm)
#pragma unroll
            for (int fn = 0; fn < 2; ++fn) {
                const int d = fn*32 + lq;
#pragma unroll
                for (int r = 0; r < 16; ++r) {
                    const int gm = m0 + fm*32 + (r&3) + 8*(r>>2) + 4*lh;
                    const int b = gm >> 10, ns = gm & 1023;
                    qd[((size_t)((b*NHEAD + y)*NSEQ + ns))*HDIM + d] = f2bf(acc[fm][fn][r]);
                }
            }
    } else {
        const int head = y - NHEAD;
#pragma unroll
        for (int fm = 0; fm < 2; ++fm)
#pragma unroll
            for (int fn = 0; fn < 2; ++fn) {
                const int d = fn*32 + lq;
#pragma unroll
                for (int r = 0; r < 16; ++r) {
                    const int gm = m0 + fm*32 + (r&3) + 8*(r>>2) + 4*lh;
                    const int b = gm >> 10, ns = gm & 1023;
                    vTd[((size_t)((b*NHEAD + head)*HDIM + d))*NSEQ + ns] = f2bf(acc[fm][fn][r]);
                }
            }
    }
}

// ---------------------------------------------------------------------------
// attn6: flash attention, KV-SPLIT across 4 waves per block (256 thr).
// Each wave: the FULL 64 q-rows (same compute:load ratio as attn4) but only
// 8 of the 32 m-tiles -> per-wave serial chain /4, wave count x4 (3584 waves,
// ~14/CU) to fix the latency-bound regime (attn4: MfmaUtil 10%, occ 8.4%).
// K/V/bias prefetched to REGISTERS (depth-1 ping-pong); pS is wave-private
// (no barrier in main loop). Epilogue: quadrant-sequential O-partial reduce
// through LDS (wave w owns quadrant (g2,fn)=(w>>1,w&1)), fp32 partial sums.
// grid (16 qt, 7 h, 8 b), block 256.
// ---------------------------------------------------------------------------
__global__ __launch_bounds__(256, 4)
void attn6(const unsigned short* __restrict__ qh_g, const unsigned short* __restrict__ vTh,
           const unsigned short* __restrict__ ekh, const unsigned short* __restrict__ bp,
           unsigned short* __restrict__ aoh, unsigned short* __restrict__ aol)
{
    __shared__ unsigned short pS[4][1024];   // 8KB  per-wave P transpose
    __shared__ float xch[3][64][17];         // ~13KB quadrant exchange (padded)
    __shared__ float lsum[4][2][32];         // 1KB  per-wave l partials
    __shared__ float linvS[2][32];

    const int tid = threadIdx.x;
    const int w = tid >> 6, lane = tid & 63;
    const int lq = lane & 31, lh = lane >> 5;
    const int qt = blockIdx.x, head = blockIdx.y, b = blockIdx.z;
    const int bh = b*NHEAD + head;
    const int mBeg = w*8;                    // this wave's m-tile range [mBeg, mBeg+8)

    short8 qf[2][4];
#pragma unroll
    for (int g2 = 0; g2 < 2; ++g2)
#pragma unroll
        for (int c = 0; c < 4; ++c)
            qf[g2][c] = *(const short8*)(qh_g +
                ((size_t)(bh*NSEQ) + qt*64 + g2*32 + lq)*HDIM + c*16 + lh*8);

    const unsigned short* kB = ekh + ((size_t)head*NSEQ + lq)*HDIM + lh*8;
    const unsigned short* vB = vTh + ((size_t)(bh*HDIM) + lq)*NSEQ;
    const unsigned short* bB = bp + ((size_t)(head*16 + qt))*65536 + lane*8;

    short8 kR[2][4], vR[2][4], bR[2][4];
#define PREF(J, par) { const int mm = ((J) < mBeg+8) ? (J) : mBeg;             \
    _Pragma("unroll") for (int c = 0; c < 4; ++c)                              \
        kR[par][c] = *(const short8*)(kB + (size_t)mm*2048 + c*16);            \
    _Pragma("unroll") for (int c2 = 0; c2 < 2; ++c2)                           \
    _Pragma("unroll") for (int h2 = 0; h2 < 2; ++h2)                           \
        vR[par][c2*2+h2] = *(const short8*)(vB + (size_t)(h2*32)*NSEQ + mm*32 + (c2*2+lh)*8); \
    _Pragma("unroll") for (int u = 0; u < 4; ++u)                              \
        bR[par][u] = *(const short8*)(bB + ((size_t)mm*4 + u)*512); }

    floatx16 O[2][2] = {};
    float ls[2] = {0.f, 0.f};

#define SEC(J, par, nxt) {                                                     \
    PREF((J)+1, nxt)                                                           \
    _Pragma("unroll") for (int g2 = 0; g2 < 2; ++g2) {                         \
        floatx16 S = {};                                                       \
        _Pragma("unroll") for (int c = 0; c < 4; ++c)                          \
            S = MFMA32(kR[par][c], qf[g2][c], S);                              \
        _Pragma("unroll") for (int g = 0; g < 4; ++g) {                        \
            unsigned short hb[4];                                              \
            _Pragma("unroll") for (int j2 = 0; j2 < 4; ++j2) {                 \
                const int i = g*4 + j2;                                        \
                float bs = h2f((unsigned short)bR[par][g2*2 + (i>>3)][i&7]);   \
                float pv = __expf(fmaf(S[i], SCALE_F, bs));                    \
                ls[g2] += pv;  hb[j2] = f2bf(pv);                              \
            }                                                                  \
            *(ushort4*)(pS[w] + g*256 + lq*8 + lh*4) = make_ushort4(hb[0],hb[1],hb[2],hb[3]); \
        }                                                                      \
        _Pragma("unroll") for (int c2 = 0; c2 < 2; ++c2) {                     \
            short8 pf = *(const short8*)(pS[w] + ((c2*2+lh)*32 + lq)*8);       \
            O[g2][0] = MFMA32(pf, vR[par][c2*2+0], O[g2][0]);                  \
            O[g2][1] = MFMA32(pf, vR[par][c2*2+1], O[g2][1]);                  \
        } } }

    PREF(mBeg, 0)
    for (int jj = 0; jj < 4; ++jj) {
        SEC(mBeg+2*jj,   0, 1)
        SEC(mBeg+2*jj+1, 1, 0)
    }
#undef SEC
#undef PREF

    // ---- cross-wave reduction -------------------------------------------
    // l partials: fold lh halves, publish per-wave, sum across waves.
    float lt0 = ls[0] + __shfl_xor(ls[0], 32);
    float lt1 = ls[1] + __shfl_xor(ls[1], 32);
    if (lh == 0) { lsum[w][0][lq] = lt0; lsum[w][1][lq] = lt1; }
    __syncthreads();
    if (w == 0) {
        float t = lsum[0][lh][lq] + lsum[1][lh][lq] + lsum[2][lh][lq] + lsum[3][lh][lq];
        linvS[lh][lq] = 1.f/t;
    }
    __syncthreads();

    // O partials: 4 quadrant-sequential rounds; wave q owns quadrant
    // (g2,fn) = (q>>1, q&1); other 3 waves publish, owner sums + stores.
#pragma unroll
    for (int q = 0; q < 4; ++q) {
        const int qg2 = q >> 1, qfn = q & 1;
        if (w != q) {
            const int slot = w - (w > q);
#pragma unroll
            for (int r = 0; r < 16; ++r) xch[slot][lane][r] = O[qg2][qfn][r];
        }
        __syncthreads();
        if (w == q) {
            floatx16 acc = O[qg2][qfn];
#pragma unroll
            for (int s = 0; s < 3; ++s)
#pragma unroll
                for (int r = 0; r < 16; ++r) acc[r] += xch[s][lane][r];
#pragma unroll
            for (int r = 0; r < 16; ++r) {
                const int qr = (r&3) + 8*(r>>2) + 4*lh;
                const float inv = linvS[qg2][qr];
                const size_t o = ((size_t)(b*NSEQ) + qt*64 + qg2*32 + qr)*DIMM
                               + head*HDIM + qfn*32 + lq;
                float v = acc[r]*inv;
                unsigned short h0 = f2bf(v);
                aoh[o] = h0;  aol[o] = f2bf(v - bf2f(h0));
            }
        }
        __syncthreads();
    }
}

// ---------------------------------------------------------------------------
// gemm2_reg: out = ao @ w_out + b_out, split-2 (3-term), REGISTER-ONLY.
// 1 wave/block, tile 64x64, BK=32, depth-1 reg prefetch. grid (128, 7).
// ---------------------------------------------------------------------------
__global__ __launch_bounds__(64, 2)
void gemm2_reg(const unsigned short* __restrict__ Ah, const unsigned short* __restrict__ Al,
               const unsigned short* __restrict__ Bh, const unsigned short* __restrict__ Bl,
               const float* __restrict__ bias, float* __restrict__ out)
{
    const int lane = threadIdx.x;
    const int lq = lane & 31, lh = lane >> 5;
    const int m0 = blockIdx.x * 64;
    const int n0 = blockIdx.y * 64;
    const unsigned short* aBh = Ah + (size_t)(m0 + lq)*KDIM + lh*8;
    const unsigned short* aBl = Al + (size_t)(m0 + lq)*KDIM + lh*8;
    const unsigned short* bBh = Bh + (size_t)(n0 + lq)*KDIM + lh*8;
    const unsigned short* bBl = Bl + (size_t)(n0 + lq)*KDIM + lh*8;

    floatx16 acc[2][2] = {};
    short8 aH[2][2][2], aL[2][2][2], bH[2][2][2], bL[2][2][2];
#define LD2(kt, par) {                                                        \
    _Pragma("unroll") for (int fm = 0; fm < 2; ++fm)                          \
    _Pragma("unroll") for (int c = 0; c < 2; ++c) {                           \
        const size_t off = (size_t)fm*32*KDIM + (kt)*32 + c*16;               \
        aH[par][fm][c] = *(const short8*)(aBh + off);                         \
        aL[par][fm][c] = *(const short8*)(aBl + off);                         \
        bH[par][fm][c] = *(const short8*)(bBh + off);                         \
        bL[par][fm][c] = *(const short8*)(bBl + off); } }

    LD2(0, 0)
#pragma unroll
    for (int kt = 0; kt < 14; ++kt) {
        const int par = kt & 1;
        if (kt < 13) LD2(kt+1, par^1)
#pragma unroll
        for (int c = 0; c < 2; ++c)
#pragma unroll
            for (int fm = 0; fm < 2; ++fm)
#pragma unroll
                for (int fn = 0; fn < 2; ++fn) {
                    acc[fm][fn] = MFMA32(aH[par][fm][c], bH[par][fn][c], acc[fm][fn]);
                    acc[fm][fn] = MFMA32(aL[par][fm][c], bH[par][fn][c], acc[fm][fn]);
                    acc[fm][fn] = MFMA32(aH[par][fm][c], bL[par][fn][c], acc[fm][fn]);
                }
    }
#undef LD2

#pragma unroll
    for (int fm = 0; fm < 2; ++fm)
#pragma unroll
        for (int fn = 0; fn < 2; ++fn) {
            const int gn = n0 + fn*32 + lq;
            const float bv = bias[gn];
#pragma unroll
            for (int r = 0; r < 16; ++r) {
                const int gm = m0 + fm*32 + (r&3) + 8*(r>>2) + 4*lh;
                out[(size_t)gm*DIMM + gn] = acc[fm][fn][r] + bv;
            }
        }
}

// ---------------------------------------------------------------------------
extern "C" void kernel_launch(void* const* d_in, const int* in_sizes, int n_in,
                              void* d_out, int out_size, void* d_ws, size_t ws_size,
                              hipStream_t stream)
{
    const float* x    = (const float*)d_in[0];
    const float* wqv  = (const float*)d_in[1];
    const float* ek   = (const float*)d_in[2];
    const float* eb   = (const float*)d_in[3];
    const float* wout = (const float*)d_in[4];
    const float* bout = (const float*)d_in[5];
    float* out = (float*)d_out;

    const size_t MK = (size_t)MROWS*KDIM;        // 3,670,016
    const size_t EK = (size_t)NHEAD*NSEQ*HDIM;   // 458,752
    unsigned short* p = (unsigned short*)d_ws;
    unsigned short* xh    = p;  p += MK;
    unsigned short* wqvTh = p;  p += (size_t)896*KDIM;
    unsigned short* woTh  = p;  p += (size_t)512*KDIM;
    unsigned short* woTl  = p;  p += (size_t)512*KDIM;
    unsigned short* ekh   = p;  p += EK;
    unsigned short* qh    = p;  p += MK;
    unsigned short* vTh   = p;  p += MK;
    unsigned short* bp    = p;  p += (size_t)NHEAD*NSEQ*NSEQ;  // fp16
    unsigned short* aoh   = p;  p += MK;
    unsigned short* aol   = p;  p += MK;

    prep_all<<<6132, 256, 0, stream>>>(x, ek, wqv, wout, eb,
                                       xh, ekh, wqvTh, woTh, woTl, bp);
    gemm1_reg<<<dim3(128, 14), 64, 0, stream>>>(xh, wqvTh, qh, vTh);
    attn6<<<dim3(16, NHEAD, BATCH), 256, 0, stream>>>(qh, vTh, ekh, bp, aoh, aol);
    gemm2_reg<<<dim3(128, 7), 64, 0, stream>>>(aoh, aol, woTh, woTl, bout, out);
}

// Round 4
// 200.238 us; speedup vs baseline: 1.8974x; 1.8974x over previous
//
#include <hip/hip_runtime.h>
#include <hip/hip_bf16.h>
#include <hip/hip_fp16.h>

#define BATCH 8
#define NSEQ 1024
#define DIMM 448
#define NHEAD 7
#define HDIM 64
#define MROWS (BATCH*NSEQ)   // 8192
#define KDIM 448
#define SCALE_F 0.125f

typedef short short8 __attribute__((ext_vector_type(8)));
typedef float floatx16 __attribute__((ext_vector_type(16)));

#define MFMA32(a,b,c) __builtin_amdgcn_mfma_f32_32x32x16_bf16(a,b,c,0,0,0)

__device__ __forceinline__ unsigned short f2bf(float f){
    __hip_bfloat16 h = __float2bfloat16(f);
    return *reinterpret_cast<unsigned short*>(&h);
}
__device__ __forceinline__ float bf2f(unsigned short u){
    __hip_bfloat16 h; *reinterpret_cast<unsigned short*>(&h) = u;
    return __bfloat162float(h);
}
__device__ __forceinline__ float h2f(unsigned short u){
    __half h; *reinterpret_cast<unsigned short*>(&h) = u;
    return __half2float(h);
}
__device__ __forceinline__ unsigned short f2h(float f){
    __half h = __float2half(f);
    return *reinterpret_cast<unsigned short*>(&h);
}

// ---------------------------------------------------------------------------
// prep_all: fused conversions (one launch).
//   [0,3584)      : x fp32 -> xh bf16 (1 float4/thread)
//   [3584,4032)   : ek fp32 -> ekh bf16
//   [4032,4228)   : wqv [448][896] -> wqvTh [896][448] bf16  (4x 64-thr units)
//   [4228,4340)   : wout [448][448] -> woTh/woTl [512][448] split bf16
//   [4340,6132)   : eb -> bp fp16, pre-scaled by 0.125, attn granule order
//                   (2x 128-thr units per block)
// bp layout: ((((h*16+qt)*32 + mt)*4 + g2*2 + jj)*512 + lane*8 + t) where
//   score q = qt*64 + g2*32 + (lane&31), m = mt*32 + (t&3)+8*(t>>2)+16*jj+4*(lane>>5)
// ---------------------------------------------------------------------------
__global__ __launch_bounds__(256)
void prep_all(const float* __restrict__ x, const float* __restrict__ ek,
              const float* __restrict__ wqv, const float* __restrict__ wout,
              const float* __restrict__ eb,
              unsigned short* __restrict__ xh, unsigned short* __restrict__ ekh,
              unsigned short* __restrict__ wqvTh, unsigned short* __restrict__ woTh,
              unsigned short* __restrict__ woTl, unsigned short* __restrict__ bp)
{
    __shared__ float T[2][64][33];
    const int bx = blockIdx.x, tid = threadIdx.x;

    if (bx < 3584) {                         // x -> bf16
        int i = bx*256 + tid;
        float4 v = ((const float4*)x)[i];
        ((ushort4*)xh)[i] = make_ushort4(f2bf(v.x), f2bf(v.y), f2bf(v.z), f2bf(v.w));
    } else if (bx < 4032) {                  // ek -> bf16
        int i = (bx-3584)*256 + tid;
        float4 v = ((const float4*)ek)[i];
        ((ushort4*)ekh)[i] = make_ushort4(f2bf(v.x), f2bf(v.y), f2bf(v.z), f2bf(v.w));
    } else if (bx < 4228) {                  // wqv transpose, single bf16
        int lid = (bx-4032)*4 + (tid>>6);    // 0..783 = kc(56) x ng(14)
        int kc = lid % 56, ng = lid / 56;
        int n = ng*64 + (tid&63);
        unsigned short h[8];
#pragma unroll
        for (int j = 0; j < 8; ++j) h[j] = f2bf(wqv[(size_t)(kc*8+j)*896 + n]);
        size_t o = (size_t)n*KDIM + kc*8;
        *(ushort4*)(wqvTh + o)     = make_ushort4(h[0],h[1],h[2],h[3]);
        *(ushort4*)(wqvTh + o + 4) = make_ushort4(h[4],h[5],h[6],h[7]);
    } else if (bx < 4340) {                  // wout transpose, split hi/lo
        int lid = (bx-4228)*4 + (tid>>6);    // 0..447 = kc(56) x ng(8)
        int kc = lid % 56, ng = lid / 56;
        int n = ng*64 + (tid&63);
        ushort4 h0={0,0,0,0}, h1={0,0,0,0}, l0={0,0,0,0}, l1={0,0,0,0};
        if (n < DIMM) {
            unsigned short h[8], l[8];
#pragma unroll
            for (int j = 0; j < 8; ++j) {
                float f = wout[(size_t)(kc*8+j)*DIMM + n];
                h[j] = f2bf(f); l[j] = f2bf(f - bf2f(h[j]));
            }
            h0 = make_ushort4(h[0],h[1],h[2],h[3]); h1 = make_ushort4(h[4],h[5],h[6],h[7]);
            l0 = make_ushort4(l[0],l[1],l[2],l[3]); l1 = make_ushort4(l[4],l[5],l[6],l[7]);
        }
        size_t o = (size_t)n*KDIM + kc*8;
        *(ushort4*)(woTh + o) = h0; *(ushort4*)(woTh + o + 4) = h1;
        *(ushort4*)(woTl + o) = l0; *(ushort4*)(woTl + o + 4) = l1;
    } else {                                 // bias prep
        const int sub = tid >> 7, st = tid & 127;
        const int lid = (bx-4340)*2 + sub;   // 0..3583
        const int mt = lid & 31, qt = (lid>>5) & 15, h = lid >> 9;
#pragma unroll
        for (int it = 0; it < 4; ++it) {
            int idx = it*128 + st;
            int row = idx >> 3, c4 = (idx & 7)*4;
            float4 v = *(const float4*)(eb + ((size_t)(h*NSEQ + qt*64 + row))*NSEQ + mt*32 + c4);
            T[sub][row][c4+0]=v.x; T[sub][row][c4+1]=v.y;
            T[sub][row][c4+2]=v.z; T[sub][row][c4+3]=v.w;
        }
        __syncthreads();
        const int g2 = st >> 6, lane = st & 63;
        const int lq = lane & 31, quad = lane >> 5;
        const int q = g2*32 + lq;
        unsigned short* dst = bp + ((((size_t)h*16 + qt)*32 + mt)*4 + g2*2)*512 + lane*8;
#pragma unroll
        for (int jj = 0; jj < 2; ++jj) {
            unsigned short o[8];
#pragma unroll
            for (int t = 0; t < 8; ++t) {
                int m = (t&3) + 8*(t>>2) + 16*jj + 4*quad;
                o[t] = f2h(T[sub][q][m] * SCALE_F);
            }
            *(ushort4*)(dst + jj*512)     = make_ushort4(o[0],o[1],o[2],o[3]);
            *(ushort4*)(dst + jj*512 + 4) = make_ushort4(o[4],o[5],o[6],o[7]);
        }
    }
}

// ---------------------------------------------------------------------------
// gemm1_reg: qv = x @ w_qv, single bf16, REGISTER-ONLY (no LDS, no barriers).
// 1 wave per block, tile 64x64, BK=32, depth-1 reg prefetch.
// grid (128, 14), block 64. y<7 -> q heads; y>=7 -> vT heads (transposed).
// ---------------------------------------------------------------------------
__global__ __launch_bounds__(64, 2)
void gemm1_reg(const unsigned short* __restrict__ Ah, const unsigned short* __restrict__ Bh,
               unsigned short* __restrict__ qd, unsigned short* __restrict__ vTd)
{
    const int lane = threadIdx.x;
    const int lq = lane & 31, lh = lane >> 5;
    const int m0 = blockIdx.x * 64;
    const int y  = blockIdx.y;
    const int n0 = y * 64;
    const unsigned short* aB = Ah + (size_t)(m0 + lq)*KDIM + lh*8;
    const unsigned short* bB = Bh + (size_t)(n0 + lq)*KDIM + lh*8;

    floatx16 acc[2][2] = {};
    short8 aR[2][2][2], bR[2][2][2];
#define LD1(kt, par) {                                                        \
    _Pragma("unroll") for (int fm = 0; fm < 2; ++fm)                          \
    _Pragma("unroll") for (int c = 0; c < 2; ++c) {                           \
        aR[par][fm][c] = *(const short8*)(aB + (size_t)fm*32*KDIM + (kt)*32 + c*16); \
        bR[par][fm][c] = *(const short8*)(bB + (size_t)fm*32*KDIM + (kt)*32 + c*16); } }

    LD1(0, 0)
#pragma unroll
    for (int kt = 0; kt < 14; ++kt) {
        const int par = kt & 1;
        if (kt < 13) LD1(kt+1, par^1)
#pragma unroll
        for (int c = 0; c < 2; ++c)
#pragma unroll
            for (int fm = 0; fm < 2; ++fm)
#pragma unroll
                for (int fn = 0; fn < 2; ++fn)
                    acc[fm][fn] = MFMA32(aR[par][fm][c], bR[par][fn][c], acc[fm][fn]);
    }
#undef LD1

    if (y < NHEAD) {
#pragma unroll
        for (int fm = 0; fm < 2; ++fm)
#pragma unroll
            for (int fn = 0; fn < 2; ++fn) {
                const int d = fn*32 + lq;
#pragma unroll
                for (int r = 0; r < 16; ++r) {
                    const int gm = m0 + fm*32 + (r&3) + 8*(r>>2) + 4*lh;
                    const int b = gm >> 10, ns = gm & 1023;
                    qd[((size_t)((b*NHEAD + y)*NSEQ + ns))*HDIM + d] = f2bf(acc[fm][fn][r]);
                }
            }
    } else {
        const int head = y - NHEAD;
#pragma unroll
        for (int fm = 0; fm < 2; ++fm)
#pragma unroll
            for (int fn = 0; fn < 2; ++fn) {
                const int d = fn*32 + lq;
#pragma unroll
                for (int r = 0; r < 16; ++r) {
                    const int gm = m0 + fm*32 + (r&3) + 8*(r>>2) + 4*lh;
                    const int b = gm >> 10, ns = gm & 1023;
                    vTd[((size_t)((b*NHEAD + head)*HDIM + d))*NSEQ + ns] = f2bf(acc[fm][fn][r]);
                }
            }
    }
}

// ---------------------------------------------------------------------------
// attn7: flash attention, B-SHARING block. 4 waves per block, all with the
// SAME (head, qt) but DIFFERENT batch b -> the b-independent K and bias
// streams are issued at identical addresses by all 4 waves and hit in the
// CU's L1 after the first touch. Per-wave code is bit-identical to attn4
// (the 56us version): full 32 m-tiles, depth-1 reg ping-pong, wave-private
// pS, NO barriers. Theory: attn is L2/L3-bandwidth-bound (~6-8 TB/s eff);
// this halves the bytes (352 -> ~180 MB).
// Bijective XCD swizzle (224 = 8*28) keeps bias/K-sharing blocks on one XCD.
// grid 224 = (2 bq, 16 qt, 7 h), block 256; wave w handles b = bq*4 + w.
// ---------------------------------------------------------------------------
__global__ __launch_bounds__(256, 2)
void attn7(const unsigned short* __restrict__ qh_g, const unsigned short* __restrict__ vTh,
           const unsigned short* __restrict__ ekh, const unsigned short* __restrict__ bp,
           unsigned short* __restrict__ aoh, unsigned short* __restrict__ aol)
{
    __shared__ unsigned short pS[4][1024];   // per-wave P transpose (8KB)
    __shared__ float linv[4][2][32];         // per-wave 1/l

    const int tid = threadIdx.x;
    const int w = tid >> 6, lane = tid & 63;
    const int lq = lane & 31, lh = lane >> 5;

    // bijective XCD swizzle: 224 blocks, 28 per XCD
    const int orig = blockIdx.x;
    const int wg = (orig & 7)*28 + (orig >> 3);
    const int bq = wg & 1, qt = (wg >> 1) & 15, head = wg >> 5;
    const int b = bq*4 + w;
    const int bh = b*NHEAD + head;

    short8 qf[2][4];
#pragma unroll
    for (int g2 = 0; g2 < 2; ++g2)
#pragma unroll
        for (int c = 0; c < 4; ++c)
            qf[g2][c] = *(const short8*)(qh_g +
                ((size_t)(bh*NSEQ) + qt*64 + g2*32 + lq)*HDIM + c*16 + lh*8);

    const unsigned short* kB = ekh + ((size_t)head*NSEQ + lq)*HDIM + lh*8;        // b-indep
    const unsigned short* vB = vTh + ((size_t)(bh*HDIM) + lq)*NSEQ;               // per-b
    const unsigned short* bB = bp + ((size_t)(head*16 + qt))*65536 + lane*8;      // b-indep

    short8 kR[2][4], vR[2][4], bR[2][4];
#define PREF(J, par) { const int mm = ((J) < 32) ? (J) : 0;                    \
    _Pragma("unroll") for (int c = 0; c < 4; ++c)                              \
        kR[par][c] = *(const short8*)(kB + (size_t)mm*2048 + c*16);            \
    _Pragma("unroll") for (int c2 = 0; c2 < 2; ++c2)                           \
    _Pragma("unroll") for (int h2 = 0; h2 < 2; ++h2)                           \
        vR[par][c2*2+h2] = *(const short8*)(vB + (size_t)(h2*32)*NSEQ + mm*32 + (c2*2+lh)*8); \
    _Pragma("unroll") for (int u = 0; u < 4; ++u)                              \
        bR[par][u] = *(const short8*)(bB + ((size_t)mm*4 + u)*512); }

    floatx16 O[2][2] = {};
    float ls[2] = {0.f, 0.f};

#define SEC(J, par, nxt) {                                                     \
    PREF((J)+1, nxt)                                                           \
    _Pragma("unroll") for (int g2 = 0; g2 < 2; ++g2) {                         \
        floatx16 S = {};                                                       \
        _Pragma("unroll") for (int c = 0; c < 4; ++c)                          \
            S = MFMA32(kR[par][c], qf[g2][c], S);                              \
        _Pragma("unroll") for (int g = 0; g < 4; ++g) {                        \
            unsigned short hb[4];                                              \
            _Pragma("unroll") for (int j2 = 0; j2 < 4; ++j2) {                 \
                const int i = g*4 + j2;                                        \
                float bs = h2f((unsigned short)bR[par][g2*2 + (i>>3)][i&7]);   \
                float pv = __expf(fmaf(S[i], SCALE_F, bs));                    \
                ls[g2] += pv;  hb[j2] = f2bf(pv);                              \
            }                                                                  \
            *(ushort4*)(pS[w] + g*256 + lq*8 + lh*4) = make_ushort4(hb[0],hb[1],hb[2],hb[3]); \
        }                                                                      \
        _Pragma("unroll") for (int c2 = 0; c2 < 2; ++c2) {                     \
            short8 pf = *(const short8*)(pS[w] + ((c2*2+lh)*32 + lq)*8);       \
            O[g2][0] = MFMA32(pf, vR[par][c2*2+0], O[g2][0]);                  \
            O[g2][1] = MFMA32(pf, vR[par][c2*2+1], O[g2][1]);                  \
        } } }

    PREF(0, 0)
    for (int jj = 0; jj < 16; ++jj) {
        SEC(2*jj,   0, 1)
        SEC(2*jj+1, 1, 0)
    }
#undef SEC
#undef PREF

    // l: partial per lane-column -> full via lh-partner, transpose via LDS
    float lt0 = ls[0] + __shfl_xor(ls[0], 32);
    float lt1 = ls[1] + __shfl_xor(ls[1], 32);
    if (lh == 0) { linv[w][0][lq] = 1.f/lt0; linv[w][1][lq] = 1.f/lt1; }

#pragma unroll
    for (int g2 = 0; g2 < 2; ++g2)
#pragma unroll
        for (int r = 0; r < 16; ++r) {
            const int qr = (r&3) + 8*(r>>2) + 4*lh;
            const float inv = linv[w][g2][qr];
            const size_t o = ((size_t)(b*NSEQ) + qt*64 + g2*32 + qr)*DIMM + head*HDIM + lq;
            float v0 = O[g2][0][r]*inv, v1 = O[g2][1][r]*inv;
            unsigned short h0 = f2bf(v0), h1 = f2bf(v1);
            aoh[o]      = h0;  aol[o]      = f2bf(v0 - bf2f(h0));
            aoh[o + 32] = h1;  aol[o + 32] = f2bf(v1 - bf2f(h1));
        }
}

// ---------------------------------------------------------------------------
// gemm2_reg: out = ao @ w_out + b_out, split-2 (3-term), REGISTER-ONLY.
// 1 wave/block, tile 64x64, BK=32, depth-1 reg prefetch. grid (128, 7).
// ---------------------------------------------------------------------------
__global__ __launch_bounds__(64, 2)
void gemm2_reg(const unsigned short* __restrict__ Ah, const unsigned short* __restrict__ Al,
               const unsigned short* __restrict__ Bh, const unsigned short* __restrict__ Bl,
               const float* __restrict__ bias, float* __restrict__ out)
{
    const int lane = threadIdx.x;
    const int lq = lane & 31, lh = lane >> 5;
    const int m0 = blockIdx.x * 64;
    const int n0 = blockIdx.y * 64;
    const unsigned short* aBh = Ah + (size_t)(m0 + lq)*KDIM + lh*8;
    const unsigned short* aBl = Al + (size_t)(m0 + lq)*KDIM + lh*8;
    const unsigned short* bBh = Bh + (size_t)(n0 + lq)*KDIM + lh*8;
    const unsigned short* bBl = Bl + (size_t)(n0 + lq)*KDIM + lh*8;

    floatx16 acc[2][2] = {};
    short8 aH[2][2][2], aL[2][2][2], bH[2][2][2], bL[2][2][2];
#define LD2(kt, par) {                                                        \
    _Pragma("unroll") for (int fm = 0; fm < 2; ++fm)                          \
    _Pragma("unroll") for (int c = 0; c < 2; ++c) {                           \
        const size_t off = (size_t)fm*32*KDIM + (kt)*32 + c*16;               \
        aH[par][fm][c] = *(const short8*)(aBh + off);                         \
        aL[par][fm][c] = *(const short8*)(aBl + off);                         \
        bH[par][fm][c] = *(const short8*)(bBh + off);                         \
        bL[par][fm][c] = *(const short8*)(bBl + off); } }

    LD2(0, 0)
#pragma unroll
    for (int kt = 0; kt < 14; ++kt) {
        const int par = kt & 1;
        if (kt < 13) LD2(kt+1, par^1)
#pragma unroll
        for (int c = 0; c < 2; ++c)
#pragma unroll
            for (int fm = 0; fm < 2; ++fm)
#pragma unroll
                for (int fn = 0; fn < 2; ++fn) {
                    acc[fm][fn] = MFMA32(aH[par][fm][c], bH[par][fn][c], acc[fm][fn]);
                    acc[fm][fn] = MFMA32(aL[par][fm][c], bH[par][fn][c], acc[fm][fn]);
                    acc[fm][fn] = MFMA32(aH[par][fm][c], bL[par][fn][c], acc[fm][fn]);
                }
    }
#undef LD2

#pragma unroll
    for (int fm = 0; fm < 2; ++fm)
#pragma unroll
        for (int fn = 0; fn < 2; ++fn) {
            const int gn = n0 + fn*32 + lq;
            const float bv = bias[gn];
#pragma unroll
            for (int r = 0; r < 16; ++r) {
                const int gm = m0 + fm*32 + (r&3) + 8*(r>>2) + 4*lh;
                out[(size_t)gm*DIMM + gn] = acc[fm][fn][r] + bv;
            }
        }
}

// ---------------------------------------------------------------------------
extern "C" void kernel_launch(void* const* d_in, const int* in_sizes, int n_in,
                              void* d_out, int out_size, void* d_ws, size_t ws_size,
                              hipStream_t stream)
{
    const float* x    = (const float*)d_in[0];
    const float* wqv  = (const float*)d_in[1];
    const float* ek   = (const float*)d_in[2];
    const float* eb   = (const float*)d_in[3];
    const float* wout = (const float*)d_in[4];
    const float* bout = (const float*)d_in[5];
    float* out = (float*)d_out;

    const size_t MK = (size_t)MROWS*KDIM;        // 3,670,016
    const size_t EK = (size_t)NHEAD*NSEQ*HDIM;   // 458,752
    unsigned short* p = (unsigned short*)d_ws;
    unsigned short* xh    = p;  p += MK;
    unsigned short* wqvTh = p;  p += (size_t)896*KDIM;
    unsigned short* woTh  = p;  p += (size_t)512*KDIM;
    unsigned short* woTl  = p;  p += (size_t)512*KDIM;
    unsigned short* ekh   = p;  p += EK;
    unsigned short* qh    = p;  p += MK;
    unsigned short* vTh   = p;  p += MK;
    unsigned short* bp    = p;  p += (size_t)NHEAD*NSEQ*NSEQ;  // fp16
    unsigned short* aoh   = p;  p += MK;
    unsigned short* aol   = p;  p += MK;

    prep_all<<<6132, 256, 0, stream>>>(x, ek, wqv, wout, eb,
                                       xh, ekh, wqvTh, woTh, woTl, bp);
    gemm1_reg<<<dim3(128, 14), 64, 0, stream>>>(xh, wqvTh, qh, vTh);
    attn7<<<224, 256, 0, stream>>>(qh, vTh, ekh, bp, aoh, aol);
    gemm2_reg<<<dim3(128, 7), 64, 0, stream>>>(aoh, aol, woTh, woTl, bout, out);
}